// Round 9
// baseline (443.651 us; speedup 1.0000x reference)
//
#include <hip/hip_runtime.h>
#include <hip/hip_fp16.h>
#include <stdint.h>

// SNNClassifier: B=16384, F=256, H=256, C=10, T=100
// Phase 1: layer-1 LIF spike bitmask into d_ws (100 x 16384 x 256 bits).
// Phase 2: persistent-state fused kernel, int8 fused-digit GEMM:
//   W*2^14 = a*64 + b (i8 digits); h = (sum a*(64z) + b*z)*2^-14 via
//   mfma_i32_16x16x64_i8, single exact i32 accumulator.
//
// R9 (R8 counters: per-SIMD MFMA floor 256K cyc, VALU floor 225K, span
// 662K = sum + 40% bubbles -> pipes NOT overlapping; occupancy ~2.6
// blocks/CU, cross-wave overlap never materialized in R5-R8):
//  1. INTRA-wave overlap: restructure tg to alternate MFMA bursts and LIF
//     chunks: kloop(j0) -> lif(prev odd t) -> kloop(j1) -> load_hw ->
//     lif(even t). Each 32-MFMA burst (~640 pipe-cyc) is followed by ~400
//     cyc of independent LIF VALU -> per-wave MFMA density ~65%, so even
//     2.6 waves/SIMD keep the pipe fed. LIF t-order unchanged (bit-exact).
//  2. kloop reads a-digit frags (4), issues 4 MFMAs, then b-digit frags:
//     peak frag live 16 regs (not 32) -> ~116 total, (256,4) holds.
//  3. spike_gen: 4 t-masks into 4 DISTINCT regs, batch the 4 stores ->
//     store-data-reg reuse hazard becomes vmcnt(3)-lagged instead of a
//     full vmcnt(0) serialization per t.
// Integer acc + identical FP order => absmax must stay EXACTLY 0.003417969.

#define BB 16384
#define FF 256
#define HH 256
#define CC 10
#define TT 100

typedef __attribute__((ext_vector_type(4))) int int4v;

// ---------------- kernel 1: layer-1 spike bitmask ----------------
// Wave owns TWO b: 8 states/thread (jb<2 x js<4). Lanes 0..7 store 8 u64
// = 64B contiguous per t; stores batched 4 t at a time.
__global__ __launch_bounds__(256) void spike_gen(
    const float* __restrict__ x, unsigned long long* __restrict__ Z) {
  const int lane = threadIdx.x & 63;
  const int wv   = threadIdx.x >> 6;
  const int b0   = blockIdx.x * 8 + wv * 2;
  const float K_VM = (float)(0.001 * 100.0);        // 0.1f, numpy-exact
  const float K_ID = (float)(1.0 - 0.001 * 200.0);  // 0.8f, numpy-exact

  float v[8], cur[8], xv[8];
#pragma unroll
  for (int jb = 0; jb < 2; ++jb)
#pragma unroll
    for (int js = 0; js < 4; ++js) {
      const int idx = jb * 4 + js;
      xv[idx] = x[(size_t)(b0 + jb) * FF + js * 64 + lane];
      v[idx] = 0.0f; cur[idx] = 0.0f;
    }

  const bool s0 = (lane & 1) != 0, s1 = (lane & 2) != 0, s2 = (lane & 4) != 0;
  unsigned long long* zp = Z + (size_t)b0 * 4;

  for (int t4 = 0; t4 < TT; t4 += 4) {
    unsigned long long mq[4];  // 4 distinct regs -> stores pipeline
#pragma unroll
    for (int k = 0; k < 4; ++k) {
      unsigned long long bal[8];
#pragma unroll
      for (int idx = 0; idx < 8; ++idx) {
        float vd   = __fadd_rn(v[idx], __fmul_rn(K_VM, __fadd_rn(-v[idx], cur[idx])));
        float idec = __fmul_rn(cur[idx], K_ID);
        bool z = (vd > 1.0f);
        bal[idx] = __ballot(z);
        v[idx]   = z ? 0.0f : vd;
        cur[idx] = __fadd_rn(idec, xv[idx]);
      }
      unsigned long long m0 = s0 ? bal[1] : bal[0];
      unsigned long long m1 = s0 ? bal[3] : bal[2];
      unsigned long long m2 = s0 ? bal[5] : bal[4];
      unsigned long long m3 = s0 ? bal[7] : bal[6];
      unsigned long long n0 = s1 ? m1 : m0;
      unsigned long long n1 = s1 ? m3 : m2;
      mq[k] = s2 ? n1 : n0;
    }
    if (lane < 8) {
#pragma unroll
      for (int k = 0; k < 4; ++k)
        zp[(size_t)(t4 + k) * (BB * 4) + lane] = mq[k];
    }
  }
}

// ---------------- kernel 2: fused temporal loop (i8) ----------------
// grid: 1024 blocks = 256 bc x 4 hc. block = 256 thr = 4 waves = 4
// b-subtiles of 16 rows; all waves share one 64-h chunk (nt=4).
// LDS slab 32KB: 32 blocks of 1024B, index (nt*2+d)*4+s, content byte
// [lane*16+i] = digit d of W[h0+nt*16+(lane&15)][s*64+(lane>>4)*16+i].
__global__ __launch_bounds__(256, 4) void snn_main(
    const uint32_t* __restrict__ Z, const float* __restrict__ Wh,
    const float* __restrict__ bh, const float* __restrict__ Wr,
    const float* __restrict__ br, float* __restrict__ out) {
  __shared__ __align__(16) char WS[32768];

  const int tid = threadIdx.x;
  const int bx  = blockIdx.x;
  const int hc  = bx & 3;
  const int bc  = bx >> 2;
  const int h0  = hc * 64;
  const int b0  = bc * 64;

  // ---- stage W -> LDS as i8 digit pair, MFMA-fragment order ----
  {
    int4v* ws4 = (int4v*)WS;
#pragma unroll
    for (int half = 0; half < 4; ++half) {
      const int u  = tid + half * 256;
      const int rr = u >> 4;
      const int q  = u & 15;
      const int s  = q >> 2, kq = q & 3;
      const int nt = rr >> 4, n = rr & 15;
      const float* wp = Wh + (size_t)(h0 + rr) * FF + s * 64 + kq * 16;
      uint32_t pa[4], pb[4];
#pragma unroll
      for (int c4 = 0; c4 < 4; ++c4) {
        float4 w4 = *(const float4*)(wp + c4 * 4);
        float wf[4] = {w4.x, w4.y, w4.z, w4.w};
        uint32_t ua = 0, ub = 0;
#pragma unroll
        for (int e = 0; e < 4; ++e) {
          float af = rintf(wf[e] * 256.0f);
          af = fminf(fmaxf(af, -127.0f), 127.0f);
          float bf = rintf(__builtin_fmaf(af, -64.0f, wf[e] * 16384.0f));
          bf = fminf(fmaxf(bf, -127.0f), 127.0f);
          ua |= ((uint32_t)((int)af) & 255u) << (8 * e);
          ub |= ((uint32_t)((int)bf) & 255u) << (8 * e);
        }
        pa[c4] = ua; pb[c4] = ub;
      }
      ws4[((nt * 2 + 0) * 4 + s) * 64 + kq * 16 + n] = *(int4v*)pa;
      ws4[((nt * 2 + 1) * 4 + s) * 64 + kq * 16 + n] = *(int4v*)pb;
    }
  }
  __syncthreads();

  const int lane = tid & 63;
  const int bsub = tid >> 6;
  const int col  = lane & 15;
  const int quad = lane >> 4;
  const bool qhi = (quad & 2) != 0;
  const uint32_t shl16 = (quad & 1) * 16;

  const int brow = b0 + bsub * 16 + col;

  const float K_VM = (float)(0.001 * 100.0);
  const float K_ID = (float)(1.0 - 0.001 * 200.0);

  float v2[4][4], ii[4][4];
  uint32_t sc[4];  // packed: byte r of sc[nt] = spike count (<=100)
#pragma unroll
  for (int nt = 0; nt < 4; ++nt) {
    sc[nt] = 0u;
#pragma unroll
    for (int r = 0; r < 4; ++r) { v2[nt][r] = 0.f; ii[nt][r] = 0.f; }
  }

  float bias[4];
#pragma unroll
  for (int nt = 0; nt < 4; ++nt) bias[nt] = bh[h0 + nt * 16 + col];

  // per-lane compacted spike halfwords, hwX[j] for 2 t-planes
  uint32_t hw0[2], hw1[2], hw2[2], hw3[2];
  const uint32_t* zrow = Z + (size_t)brow * 8;

  auto load_hw = [&](int tgi) {
#pragma unroll
    for (int j = 0; j < 2; ++j) {
      const uint32_t* p = zrow + ((size_t)tgi * 2 + j) * (size_t)(BB * 8);
      uint4 a = *(const uint4*)p;
      uint4 b4 = *(const uint4*)(p + 4);
      hw0[j] = (qhi ? a.y : a.x) >> shl16;
      hw1[j] = (qhi ? a.w : a.z) >> shl16;
      hw2[j] = (qhi ? b4.y : b4.x) >> shl16;
      hw3[j] = (qhi ? b4.w : b4.z) >> shl16;
    }
  };
  load_hw(0);

  const char* wsl = WS + lane * 16;

  int4v accA[4], accB[4];

  auto zero4 = [](int4v (&ac)[4]) {
#pragma unroll
    for (int nt = 0; nt < 4; ++nt) ac[nt] = (int4v){0, 0, 0, 0};
  };

  // one t-plane's K loop: 4 s-steps, a-digit group (4 reads + 4 MFMA)
  // then b-digit group -> peak frag live = 16 regs.
  auto kloop = [&](int4v (&ac)[4], uint32_t a0, uint32_t a1, uint32_t a2,
                   uint32_t a3) {
#pragma unroll 1
    for (int s = 0; s < 4; ++s) {
      const int4v* bp = (const int4v*)(wsl + s * 1024);
      uint32_t t0 = (s & 1) ? a1 : a0;
      uint32_t t1 = (s & 1) ? a3 : a2;
      uint32_t h16 = (s & 2) ? t1 : t0;
      int4v za, zb_;
#pragma unroll
      for (int p = 0; p < 4; ++p) {
        uint32_t nib = (h16 >> (4 * p)) & 15u;
        uint32_t zbyte = __umul24(nib, 0x204081u) & 0x01010101u;
        zb_[p] = (int)zbyte;
        za[p]  = (int)(zbyte << 6);  // 64*z, fits i8
      }
      int4v Ba[4];
#pragma unroll
      for (int nt = 0; nt < 4; ++nt) Ba[nt] = bp[(nt * 2 + 0) * 256];
#pragma unroll
      for (int nt = 0; nt < 4; ++nt)
        ac[nt] = __builtin_amdgcn_mfma_i32_16x16x64_i8(za, Ba[nt], ac[nt],
                                                       0, 0, 0);
      int4v Bb[4];
#pragma unroll
      for (int nt = 0; nt < 4; ++nt) Bb[nt] = bp[(nt * 2 + 1) * 256];
#pragma unroll
      for (int nt = 0; nt < 4; ++nt)
        ac[nt] = __builtin_amdgcn_mfma_i32_16x16x64_i8(zb_, Bb[nt], ac[nt],
                                                       0, 0, 0);
    }
  };

  // one t-plane's LIF over 16 (nt,r) elements, numpy op order.
  auto lif = [&](int4v (&ac)[4]) {
#pragma unroll
    for (int nt = 0; nt < 4; ++nt) {
#pragma unroll
      for (int r = 0; r < 4; ++r) {
        float h  = __builtin_fmaf((float)ac[nt][r], 6.103515625e-05f,
                                  bias[nt]);
        float vv = v2[nt][r], ci = ii[nt][r];
        float vd   = __fadd_rn(vv, __fmul_rn(K_VM, __fadd_rn(-vv, ci)));
        float idec = __fmul_rn(ci, K_ID);
        bool z = (vd > 1.0f);
        v2[nt][r] = z ? 0.0f : vd;
        ii[nt][r] = __fadd_rn(idec, h);
        sc[nt] += (z ? 1u : 0u) << (8 * r);
      }
    }
  };

  // software-pipelined t loop: every MFMA burst is followed by an
  // independent LIF chunk (intra-wave MFMA/VALU overlap).
  zero4(accA);
  kloop(accA, hw0[0], hw1[0], hw2[0], hw3[0]);       // t = 0
#pragma unroll 1
  for (int tg = 0; tg < TT / 2; ++tg) {
    zero4(accB);
    kloop(accB, hw0[1], hw1[1], hw2[1], hw3[1]);     // t = 2tg+1
    if (tg < TT / 2 - 1) load_hw(tg + 1);
    lif(accA);                                        // t = 2tg
    if (tg < TT / 2 - 1) {
      zero4(accA);
      kloop(accA, hw0[0], hw1[0], hw2[0], hw3[0]);   // t = 2tg+2
    }
    lif(accB);                                        // t = 2tg+1
  }

  // ---- epilogue: readout GEMM, fused ----
  float mean[4][4];
#pragma unroll
  for (int nt = 0; nt < 4; ++nt)
#pragma unroll
    for (int r = 0; r < 4; ++r)
      mean[nt][r] = __fdiv_rn((float)((sc[nt] >> (8 * r)) & 255u), 100.0f);

#pragma unroll 1
  for (int c = 0; c < CC; ++c) {
    float wc[4];
#pragma unroll
    for (int nt = 0; nt < 4; ++nt) wc[nt] = Wr[c * HH + h0 + nt * 16 + col];
#pragma unroll
    for (int r = 0; r < 4; ++r) {
      float s = 0.f;
#pragma unroll
      for (int nt = 0; nt < 4; ++nt) s = fmaf(mean[nt][r], wc[nt], s);
      s += __shfl_xor(s, 1);
      s += __shfl_xor(s, 2);
      s += __shfl_xor(s, 4);
      s += __shfl_xor(s, 8);
      if (col == 0) {
        int b = b0 + bsub * 16 + quad * 4 + r;
        float add = s + ((hc == 0) ? br[c] : 0.0f);
        atomicAdd(&out[b * CC + c], add);
      }
    }
  }
}

extern "C" void kernel_launch(void* const* d_in, const int* in_sizes, int n_in,
                              void* d_out, int out_size, void* d_ws, size_t ws_size,
                              hipStream_t stream) {
  const float* x  = (const float*)d_in[0];
  const float* Wh = (const float*)d_in[1];
  const float* bh = (const float*)d_in[2];
  const float* Wr = (const float*)d_in[3];
  const float* br = (const float*)d_in[4];
  float* out = (float*)d_out;

  // workspace: spike bitmask, 100*16384*32B = 52.4 MB
  unsigned long long* Z = (unsigned long long*)d_ws;

  hipMemsetAsync(d_out, 0, (size_t)out_size * sizeof(float), stream);
  spike_gen<<<BB / 8, 256, 0, stream>>>(x, Z);
  snn_main<<<1024, 256, 0, stream>>>((const uint32_t*)Z, Wh, bh, Wr, br, out);
}